// Round 3
// baseline (2396.081 us; speedup 1.0000x reference)
//
#include <hip/hip_runtime.h>
#include <hip/hip_fp16.h>
#include <math.h>

// Round 3: fix round-2's register spill (VGPR capped at 128 -> 128-VGPR weight
// array went to scratch -> 2.4GB HBM stream). Now 1024 threads/block, each
// thread owns a QUARTER weight row (128 f16 = 64 half2 = 64 VGPR), total
// ~104 VGPR < 128 cap. Thread t -> row c=t&255, quarter j=t>>8 (j<2: k=0
// vs running_sum; j>=2: k=1 vs val). Dot partials combine via LDS.
// rs/val stay fp32 (LDS broadcast reads, wave-uniform segment address).

namespace {

constexpr int S_LEN = 128;
constexpr int V_N   = 256;

__device__ __forceinline__ float sigmoidf_(float x) {
    return 1.0f / (1.0f + expf(-x));
}

__global__ void __launch_bounds__(1024) scan_kernel(
    const float* __restrict__ av_g,   // [S,B,V]
    const float* __restrict__ xn_g,
    const float* __restrict__ xv_g,
    const float* __restrict__ yn_g,
    const float* __restrict__ yv_g,
    const float* __restrict__ sv_g,   // [32,256]
    const float* __restrict__ sw_g,   // [256,512]
    const float* __restrict__ snw_g,  // [256,2]
    const float* __restrict__ def_g,  // [4,256]
    const float* __restrict__ vnw_g,  // [6,3]
    float* __restrict__ out)          // [B,S,V]
{
    const int b    = blockIdx.x;
    const int t    = threadIdx.x;     // 0..1023
    const int wave = t >> 6;
    const int lane = t & 63;
    const int c    = t & 255;         // choice row
    const int j    = t >> 8;          // quarter 0..3 (uniform per wave)
    constexpr float EPS = 1e-8f;

    __shared__ __align__(16) float rs_lds[V_N];
    __shared__ __align__(16) float val_lds[V_N];
    __shared__ float partials[4][256];    // [quarter][row]
    __shared__ float wsum[4][8];
    __shared__ float gw[32];
    __shared__ float sv_lds[32][V_N];
    __shared__ float nwv_lds[18];

    // ---- one-time setup ----
    for (int i = t; i < 32 * V_N; i += 1024) sv_lds[i >> 8][i & 255] = sv_g[i];
    if (t < 18) nwv_lds[t] = sigmoidf_(vnw_g[t]);

    // thread (c,j) holds row c, float elements [j*128, j*128+128) of the
    // 512-float row (k=0 occupies [0,256), k=1 occupies [256,512)).
    const float4* wsrc = reinterpret_cast<const float4*>(
        sw_g + (size_t)c * 512 + (size_t)j * 128);
    __half2 w[64];                        // 64 VGPRs of fp16 weights
    float nsq = 0.f;
#pragma unroll
    for (int i = 0; i < 32; ++i) {
        const float4 a = wsrc[i];
        const __half2 h0 = __floats2half2_rn(a.x, a.y);
        const __half2 h1 = __floats2half2_rn(a.z, a.w);
        w[2 * i]     = h0;
        w[2 * i + 1] = h1;
        float2 f;
        f = __half22float2(h0); nsq += f.x * f.x + f.y * f.y;
        f = __half22float2(h1); nsq += f.x * f.x + f.y * f.y;
    }
    partials[j][c] = nsq;
    __syncthreads();

    float invw0 = 0.f, invw1 = 0.f, nws0 = 0.f, nws1 = 0.f;
    float d_reg[4] = {0.f, 0.f, 0.f, 0.f};
    if (t < 256) {
        invw0 = 1.0f / fmaxf(sqrtf(partials[0][t] + partials[1][t]), EPS);
        invw1 = 1.0f / fmaxf(sqrtf(partials[2][t] + partials[3][t]), EPS);
        nws0  = sigmoidf_(snw_g[2 * t]);
        nws1  = sigmoidf_(snw_g[2 * t + 1]);
#pragma unroll
        for (int d = 0; d < 4; ++d) d_reg[d] = def_g[d * V_N + t];
    }

    // wave-uniform segment pointer for phase 3 (j uniform per wave)
    const float4* seg4 = reinterpret_cast<const float4*>(
        (j < 2) ? (rs_lds + (j << 7)) : (val_lds + ((j - 2) << 7)));

    float rs = 1e-6f;
    float av = 0.f, xn = 0.f, xv = 0.f, yn = 0.f, yv = 0.f;
    if (t < 256) {
        const size_t base0 = (size_t)b * 256 + t;
        av = av_g[base0]; xn = xn_g[base0]; xv = xv_g[base0];
        yn = yn_g[base0]; yv = yv_g[base0];
    }

    for (int s = 0; s < S_LEN; ++s) {
        // ---- phase 1: 7 block reductions over V (t<256) ----
        if (t < 256) {
            float q0 = av * xn, q1 = av * yn, q2 = xn * yn;
            float q3 = av * av, q4 = xn * xn, q5 = yn * yn, q6 = rs * rs;
#pragma unroll
            for (int off = 32; off >= 1; off >>= 1) {
                q0 += __shfl_xor(q0, off);
                q1 += __shfl_xor(q1, off);
                q2 += __shfl_xor(q2, off);
                q3 += __shfl_xor(q3, off);
                q4 += __shfl_xor(q4, off);
                q5 += __shfl_xor(q5, off);
                q6 += __shfl_xor(q6, off);
            }
            if (lane == 0) {
                wsum[wave][0] = q0; wsum[wave][1] = q1; wsum[wave][2] = q2;
                wsum[wave][3] = q3; wsum[wave][4] = q4; wsum[wave][5] = q5;
                wsum[wave][6] = q6;
            }
        }
        __syncthreads();   // sync1

        float inv_rs = 0.f;
        // ---- phase 2: cs, var-choice blend, stage rs/val (t<256) ----
        if (t < 256) {
            float axn = 0, ayn = 0, xny = 0, naa = 0, nxx = 0, nyy = 0, nrs = 0;
#pragma unroll
            for (int w4 = 0; w4 < 4; ++w4) {
                axn += wsum[w4][0]; ayn += wsum[w4][1]; xny += wsum[w4][2];
                naa += wsum[w4][3]; nxx += wsum[w4][4]; nyy += wsum[w4][5];
                nrs += wsum[w4][6];
            }
            const float na = fmaxf(sqrtf(naa), EPS);
            const float nx = fmaxf(sqrtf(nxx), EPS);
            const float ny = fmaxf(sqrtf(nyy), EPS);
            float csarr[3];
            csarr[0] = axn / (na * nx);
            csarr[1] = ayn / (na * ny);
            csarr[2] = xny / (nx * ny);
            inv_rs = 1.0f / fmaxf(sqrtf(nrs), EPS);

            float vc[6];
#pragma unroll
            for (int jj = 0; jj < 6; ++jj) {
                float p = 1.0f;
#pragma unroll
                for (int k = 0; k < 3; ++k) {
                    const float a   = nwv_lds[jj * 3 + k];
                    const float csk = csarr[k];
                    p = p * (a * csk + (1.0f - a) * (1.0f - csk));
                }
                vc[jj] = p;
            }
            const float val = vc[0] * xv + vc[1] * yv + vc[2] * d_reg[0]
                            + vc[3] * d_reg[1] + vc[4] * d_reg[2] + vc[5] * d_reg[3];
            rs_lds[t]  = rs;
            val_lds[t] = val;
            float qv = val * val;
#pragma unroll
            for (int off = 32; off >= 1; off >>= 1) qv += __shfl_xor(qv, off);
            if (lane == 0) wsum[wave][7] = qv;
        }
        __syncthreads();   // sync2

        // ---- phase 3: quarter-row dots (all 1024 threads) ----
        // prefetch next step's inputs under the dot compute
        float avn = av, xnn = xn, xvn = xv, ynn = yn, yvn = yv;
        if (t < 256) {
            const int sn = (s + 1 < S_LEN) ? s + 1 : s;
            const size_t basen = (size_t)sn * (256 * 256) + (size_t)b * 256 + t;
            avn = av_g[basen]; xnn = xn_g[basen]; xvn = xv_g[basen];
            ynn = yn_g[basen]; yvn = yv_g[basen];
        }
        float dot = 0.f;
#pragma unroll
        for (int i = 0; i < 32; ++i) {
            const float4 r  = seg4[i];
            const float2 a0 = __half22float2(w[2 * i]);
            const float2 a1 = __half22float2(w[2 * i + 1]);
            dot += a0.x * r.x + a0.y * r.y + a1.x * r.z + a1.y * r.w;
        }
        partials[j][c] = dot;
        __syncthreads();   // sync3

        // ---- phase 3b: combine quarters, NAND, redundancy-reduce (t<256) ----
        if (t < 256) {
            const float inv_val = 1.0f / fmaxf(sqrtf(wsum[0][7] + wsum[1][7] +
                                                     wsum[2][7] + wsum[3][7]), EPS);
            const float d0 = partials[0][t] + partials[1][t];
            const float d1 = partials[2][t] + partials[3][t];
            float c0 = d0 * inv_rs  * invw0;
            float c1 = d1 * inv_val * invw1;
            c0 = (c0 > 0.f) ? c0 : 0.01f * c0;   // leaky_relu
            c1 = (c1 > 0.f) ? c1 : 0.01f * c1;
            const float i0 = nws0 * c0 + (1.0f - nws0) * (1.0f - c0);
            const float i1 = nws1 * c1 + (1.0f - nws1) * (1.0f - c1);
            float choice = i0 * i1;
            choice += __shfl_xor(choice, 1);
            choice += __shfl_xor(choice, 2);
            choice += __shfl_xor(choice, 4);
            if ((t & 7) == 0) gw[t >> 3] = choice;
        }
        __syncthreads();   // sync4

        // ---- phase 4: new_rs, store, rotate prefetched inputs (t<256) ----
        if (t < 256) {
            float nrs_new = 0.f;
#pragma unroll
            for (int nc = 0; nc < 32; ++nc) nrs_new += sv_lds[nc][t] * gw[nc];
            rs = nrs_new;
            out[((size_t)b * S_LEN + s) * V_N + t] = rs;
            av = avn; xn = xnn; xv = xvn; yn = ynn; yv = yvn;
        }
        // LDS hazards: every buffer has >=2 barriers between reuse (checked).
    }
}

} // namespace

extern "C" void kernel_launch(void* const* d_in, const int* in_sizes, int n_in,
                              void* d_out, int out_size, void* d_ws, size_t ws_size,
                              hipStream_t stream) {
    (void)in_sizes; (void)n_in; (void)d_ws; (void)ws_size; (void)out_size;
    const float* av  = (const float*)d_in[0];
    const float* xn  = (const float*)d_in[1];
    const float* xv  = (const float*)d_in[2];
    const float* yn  = (const float*)d_in[3];
    const float* yv  = (const float*)d_in[4];
    const float* sv  = (const float*)d_in[5];
    const float* sw  = (const float*)d_in[6];
    const float* snw = (const float*)d_in[7];
    const float* def = (const float*)d_in[8];
    const float* vnw = (const float*)d_in[9];
    scan_kernel<<<dim3(256), dim3(1024), 0, stream>>>(
        av, xn, xv, yn, yv, sv, sw, snw, def, vnw, (float*)d_out);
}

// Round 4
// 1983.959 us; speedup vs baseline: 1.2077x; 1.2077x over previous
//
#include <hip/hip_runtime.h>
#include <hip/hip_fp16.h>
#include <math.h>

// Round 4: same structure as round 3 (1024 thr/block, quarter weight row per
// thread in fp16 registers = 64 VGPR), but FIX THE VGPR CAP:
// __launch_bounds__(1024, 4) -> min 4 waves/EU -> 128-VGPR cap (was 64, which
// spilled the weight array to scratch -> 3.4GB HBM stream). Also trimmed
// non-weight register pressure: default vecs + per-row norm/sigmoid params
// moved to LDS; dot uses 4 independent accumulators (no dependent FMA chain).

namespace {

constexpr int S_LEN = 128;
constexpr int V_N   = 256;

__device__ __forceinline__ float sigmoidf_(float x) {
    return 1.0f / (1.0f + expf(-x));
}

__global__ void __launch_bounds__(1024, 4) scan_kernel(
    const float* __restrict__ av_g,   // [S,B,V]
    const float* __restrict__ xn_g,
    const float* __restrict__ xv_g,
    const float* __restrict__ yn_g,
    const float* __restrict__ yv_g,
    const float* __restrict__ sv_g,   // [32,256]
    const float* __restrict__ sw_g,   // [256,512]
    const float* __restrict__ snw_g,  // [256,2]
    const float* __restrict__ def_g,  // [4,256]
    const float* __restrict__ vnw_g,  // [6,3]
    float* __restrict__ out)          // [B,S,V]
{
    const int b    = blockIdx.x;
    const int t    = threadIdx.x;     // 0..1023
    const int wave = t >> 6;
    const int lane = t & 63;
    const int c    = t & 255;         // choice row
    const int j    = t >> 8;          // quarter 0..3 (uniform per wave)
    constexpr float EPS = 1e-8f;

    __shared__ __align__(16) float rs_lds[V_N];
    __shared__ __align__(16) float val_lds[V_N];
    __shared__ float partials[4][256];    // [quarter][row]
    __shared__ float wsum[4][8];
    __shared__ float gw[32];
    __shared__ float sv_lds[32][V_N];
    __shared__ float nwv_lds[18];
    __shared__ float def_lds[4][V_N];
    __shared__ float rowp_lds[4][256];    // invw0, invw1, nws0, nws1 per row

    // ---- one-time setup ----
    for (int i = t; i < 32 * V_N; i += 1024) sv_lds[i >> 8][i & 255] = sv_g[i];
    def_lds[t >> 8][t & 255] = def_g[t];          // t spans exactly 4*256
    if (t < 18) nwv_lds[t] = sigmoidf_(vnw_g[t]);

    // thread (c,j) holds row c, float elements [j*128, j*128+128) of the
    // 512-float row (k=0 occupies [0,256) ~ rs; k=1 occupies [256,512) ~ val).
    const float4* wsrc = reinterpret_cast<const float4*>(
        sw_g + (size_t)c * 512 + (size_t)j * 128);
    __half2 w[64];                        // 64 VGPRs of fp16 weights
    float nsq = 0.f;
#pragma unroll
    for (int i = 0; i < 32; ++i) {
        const float4 a = wsrc[i];
        const __half2 h0 = __floats2half2_rn(a.x, a.y);
        const __half2 h1 = __floats2half2_rn(a.z, a.w);
        w[2 * i]     = h0;
        w[2 * i + 1] = h1;
        float2 f;
        f = __half22float2(h0); nsq += f.x * f.x + f.y * f.y;
        f = __half22float2(h1); nsq += f.x * f.x + f.y * f.y;
    }
    partials[j][c] = nsq;
    __syncthreads();

    if (t < 256) {
        rowp_lds[0][t] = 1.0f / fmaxf(sqrtf(partials[0][t] + partials[1][t]), EPS);
        rowp_lds[1][t] = 1.0f / fmaxf(sqrtf(partials[2][t] + partials[3][t]), EPS);
        rowp_lds[2][t] = sigmoidf_(snw_g[2 * t]);
        rowp_lds[3][t] = sigmoidf_(snw_g[2 * t + 1]);
    }
    // rowp/def read later by the same threads (or after barriers); partials'
    // phase-3 overwrite is separated from these reads by >=2 barriers.

    // wave-uniform segment pointer for phase 3 (j uniform per wave)
    const float4* seg4 = reinterpret_cast<const float4*>(
        (j < 2) ? (rs_lds + (j << 7)) : (val_lds + ((j - 2) << 7)));

    float rs = 1e-6f;
    float av = 0.f, xn = 0.f, xv = 0.f, yn = 0.f, yv = 0.f;
    if (t < 256) {
        const size_t base0 = (size_t)b * 256 + t;
        av = av_g[base0]; xn = xn_g[base0]; xv = xv_g[base0];
        yn = yn_g[base0]; yv = yv_g[base0];
    }

    for (int s = 0; s < S_LEN; ++s) {
        // ---- phase 1: 7 block reductions over V (t<256) ----
        if (t < 256) {
            float q0 = av * xn, q1 = av * yn, q2 = xn * yn;
            float q3 = av * av, q4 = xn * xn, q5 = yn * yn, q6 = rs * rs;
#pragma unroll
            for (int off = 32; off >= 1; off >>= 1) {
                q0 += __shfl_xor(q0, off);
                q1 += __shfl_xor(q1, off);
                q2 += __shfl_xor(q2, off);
                q3 += __shfl_xor(q3, off);
                q4 += __shfl_xor(q4, off);
                q5 += __shfl_xor(q5, off);
                q6 += __shfl_xor(q6, off);
            }
            if (lane == 0) {
                wsum[wave][0] = q0; wsum[wave][1] = q1; wsum[wave][2] = q2;
                wsum[wave][3] = q3; wsum[wave][4] = q4; wsum[wave][5] = q5;
                wsum[wave][6] = q6;
            }
        }
        __syncthreads();   // sync1

        float inv_rs = 0.f;
        // ---- phase 2: cs, var-choice blend, stage rs/val (t<256) ----
        if (t < 256) {
            float axn = 0, ayn = 0, xny = 0, naa = 0, nxx = 0, nyy = 0, nrs = 0;
#pragma unroll
            for (int w4 = 0; w4 < 4; ++w4) {
                axn += wsum[w4][0]; ayn += wsum[w4][1]; xny += wsum[w4][2];
                naa += wsum[w4][3]; nxx += wsum[w4][4]; nyy += wsum[w4][5];
                nrs += wsum[w4][6];
            }
            const float na = fmaxf(sqrtf(naa), EPS);
            const float nx = fmaxf(sqrtf(nxx), EPS);
            const float ny = fmaxf(sqrtf(nyy), EPS);
            float csarr[3];
            csarr[0] = axn / (na * nx);
            csarr[1] = ayn / (na * ny);
            csarr[2] = xny / (nx * ny);
            inv_rs = 1.0f / fmaxf(sqrtf(nrs), EPS);

            float vc[6];
#pragma unroll
            for (int jj = 0; jj < 6; ++jj) {
                float p = 1.0f;
#pragma unroll
                for (int k = 0; k < 3; ++k) {
                    const float a   = nwv_lds[jj * 3 + k];
                    const float csk = csarr[k];
                    p = p * (a * csk + (1.0f - a) * (1.0f - csk));
                }
                vc[jj] = p;
            }
            const float val = vc[0] * xv + vc[1] * yv
                            + vc[2] * def_lds[0][t] + vc[3] * def_lds[1][t]
                            + vc[4] * def_lds[2][t] + vc[5] * def_lds[3][t];
            rs_lds[t]  = rs;
            val_lds[t] = val;
            float qv = val * val;
#pragma unroll
            for (int off = 32; off >= 1; off >>= 1) qv += __shfl_xor(qv, off);
            if (lane == 0) wsum[wave][7] = qv;
        }
        __syncthreads();   // sync2

        // ---- phase 3: quarter-row dots (all 1024 threads) ----
        // prefetch next step's inputs under the dot compute (t<256)
        float avn = av, xnn = xn, xvn = xv, ynn = yn, yvn = yv;
        if (t < 256) {
            const int sn = (s + 1 < S_LEN) ? s + 1 : s;
            const size_t basen = (size_t)sn * (256 * 256) + (size_t)b * 256 + t;
            avn = av_g[basen]; xnn = xn_g[basen]; xvn = xv_g[basen];
            ynn = yn_g[basen]; yvn = yv_g[basen];
        }
        float dA = 0.f, dB = 0.f, dC = 0.f, dD = 0.f;
#pragma unroll
        for (int i = 0; i < 32; i += 2) {
            const float4 r0 = seg4[i];
            const float4 r1 = seg4[i + 1];
            const float2 a0 = __half22float2(w[2 * i]);
            const float2 a1 = __half22float2(w[2 * i + 1]);
            const float2 b0 = __half22float2(w[2 * i + 2]);
            const float2 b1 = __half22float2(w[2 * i + 3]);
            dA += a0.x * r0.x + a0.y * r0.y;
            dB += a1.x * r0.z + a1.y * r0.w;
            dC += b0.x * r1.x + b0.y * r1.y;
            dD += b1.x * r1.z + b1.y * r1.w;
        }
        partials[j][c] = (dA + dB) + (dC + dD);
        __syncthreads();   // sync3

        // ---- phase 3b: combine quarters, NAND, redundancy-reduce (t<256) ----
        if (t < 256) {
            const float inv_val = 1.0f / fmaxf(sqrtf(wsum[0][7] + wsum[1][7] +
                                                     wsum[2][7] + wsum[3][7]), EPS);
            const float d0 = partials[0][t] + partials[1][t];
            const float d1 = partials[2][t] + partials[3][t];
            float c0 = d0 * inv_rs  * rowp_lds[0][t];
            float c1 = d1 * inv_val * rowp_lds[1][t];
            c0 = (c0 > 0.f) ? c0 : 0.01f * c0;   // leaky_relu
            c1 = (c1 > 0.f) ? c1 : 0.01f * c1;
            const float nw0 = rowp_lds[2][t];
            const float nw1 = rowp_lds[3][t];
            const float i0 = nw0 * c0 + (1.0f - nw0) * (1.0f - c0);
            const float i1 = nw1 * c1 + (1.0f - nw1) * (1.0f - c1);
            float choice = i0 * i1;
            choice += __shfl_xor(choice, 1);
            choice += __shfl_xor(choice, 2);
            choice += __shfl_xor(choice, 4);
            if ((t & 7) == 0) gw[t >> 3] = choice;
        }
        __syncthreads();   // sync4

        // ---- phase 4: new_rs, store, rotate prefetched inputs (t<256) ----
        if (t < 256) {
            float nrs_new = 0.f;
#pragma unroll
            for (int nc = 0; nc < 32; ++nc) nrs_new += sv_lds[nc][t] * gw[nc];
            rs = nrs_new;
            out[((size_t)b * S_LEN + s) * V_N + t] = rs;
            av = avn; xn = xnn; xv = xvn; yn = ynn; yv = yvn;
        }
        // LDS hazards: every buffer has >=2 barriers between write and reuse.
    }
}

} // namespace

extern "C" void kernel_launch(void* const* d_in, const int* in_sizes, int n_in,
                              void* d_out, int out_size, void* d_ws, size_t ws_size,
                              hipStream_t stream) {
    (void)in_sizes; (void)n_in; (void)d_ws; (void)ws_size; (void)out_size;
    const float* av  = (const float*)d_in[0];
    const float* xn  = (const float*)d_in[1];
    const float* xv  = (const float*)d_in[2];
    const float* yn  = (const float*)d_in[3];
    const float* yv  = (const float*)d_in[4];
    const float* sv  = (const float*)d_in[5];
    const float* sw  = (const float*)d_in[6];
    const float* snw = (const float*)d_in[7];
    const float* def = (const float*)d_in[8];
    const float* vnw = (const float*)d_in[9];
    scan_kernel<<<dim3(256), dim3(1024), 0, stream>>>(
        av, xn, xv, yn, yv, sv, sw, snw, def, vnw, (float*)d_out);
}